// Round 9
// baseline (292.829 us; speedup 1.0000x reference)
//
#include <hip/hip_runtime.h>
#include <hip/hip_fp16.h>
#include <math.h>

#define B_ 4
#define S_ 8192
#define D_ 512
#define H_ 8
#define U_ 45            // int(5*ln(8193)) = 45
#define NCHUNK 16        // 512 keys per attention block

typedef unsigned short ushortT;
typedef __attribute__((ext_vector_type(8))) _Float16 half8;
typedef __attribute__((ext_vector_type(8))) unsigned short ushort8;
typedef __attribute__((ext_vector_type(4))) float f32x4;

__device__ __forceinline__ ushortT f2h(float f) {
    return __half_as_ushort(__float2half(f));    // RNE
}
__device__ __forceinline__ float h2f(ushortT u) {
    return __half2float(__ushort_as_half(u));
}

__device__ __forceinline__ void gload_lds16(const ushortT* g, ushortT* l) {
    __builtin_amdgcn_global_load_lds(
        (const __attribute__((address_space(1))) void*)g,
        (__attribute__((address_space(3))) void*)l,
        16, 0, 0);
}

// ---------------------------------------------------------------------------
// Fused pre-pass: blocks [0,8192): X fp32 -> fp16 (block 0 zeroes vsum +
// outbase).  Blocks [8192, 8960): weight transpose+convert WT[n][k]=W[k][n].
// ---------------------------------------------------------------------------
__global__ __launch_bounds__(256) void prep_kernel(
    const float* __restrict__ X, ushortT* __restrict__ Xf,
    const float* __restrict__ Wq, const float* __restrict__ Wk,
    const float* __restrict__ Wv,
    ushortT* __restrict__ WqT, ushortT* __restrict__ WkT,
    ushortT* __restrict__ WvT,
    float* __restrict__ vsum, float* __restrict__ outbase)
{
    __shared__ float t[32][33];
    const int bx = blockIdx.x;
    if (bx < 8192) {
        if (bx == 0) {
            float4 z = {0.f, 0.f, 0.f, 0.f};
            *(float4*)&vsum[threadIdx.x * 8]        = z;
            *(float4*)&vsum[threadIdx.x * 8 + 4]    = z;
            *(float4*)&outbase[threadIdx.x * 8]     = z;
            *(float4*)&outbase[threadIdx.x * 8 + 4] = z;
        }
        size_t i = ((size_t)bx * 256 + threadIdx.x) * 8;
        float4 a = *(const float4*)(X + i);
        float4 b = *(const float4*)(X + i + 4);
        *(ushort4*)(Xf + i)     = make_ushort4(f2h(a.x), f2h(a.y), f2h(a.z), f2h(a.w));
        *(ushort4*)(Xf + i + 4) = make_ushort4(f2h(b.x), f2h(b.y), f2h(b.z), f2h(b.w));
    } else {
        const int idx = bx - 8192;
        const int z = idx >> 8, rem = idx & 255;
        const int r0 = (rem >> 4) * 32, c0 = (rem & 15) * 32;
        const float* W = (z == 0) ? Wq : (z == 1) ? Wk : Wv;
        ushortT* O = (z == 0) ? WqT : (z == 1) ? WkT : WvT;
        const int tx = threadIdx.x & 31, ty4 = (threadIdx.x >> 5) * 4;
#pragma unroll
        for (int i = 0; i < 4; ++i)
            t[ty4 + i][tx] = W[(size_t)(r0 + ty4 + i) * 512 + c0 + tx];
        __syncthreads();
#pragma unroll
        for (int i = 0; i < 4; ++i)
            O[(size_t)(c0 + ty4 + i) * 512 + r0 + tx] = f2h(t[tx][ty4 + i]);
    }
}

// ---------------------------------------------------------------------------
// FUSED QKV MFMA: one pass stages A (Xf tile) ONCE and runs 3 B-streams
// (WqT/WkT/WvT) -> 96 MFMA per 64KB staged per iter (6:1 MFMA:gload, vs 4:1
// in the 3-pass version).  grid (256 m-tiles, 4 n-tiles), 128x128 tile,
// BK=64, 4 waves 2x2, wave = 64x64 per matrix (3 acc sets, ~240 VGPR,
// 2 waves/SIMD).  8-chunk rotate swizzle (verified conflict-free).
// Epilogues: Q -> head-major fp16 + sparsity; K -> head-major fp16;
// V -> LDS transpose (post-loop staging LDS reuse) -> VT[bh][64][8192] + vsum.
// ---------------------------------------------------------------------------
__global__ __launch_bounds__(256, 2) void qkv_mfma(
    const ushortT* __restrict__ Xf,
    const ushortT* __restrict__ WqT, const ushortT* __restrict__ WkT,
    const ushortT* __restrict__ WvT,
    const float* __restrict__ bq, const float* __restrict__ bk,
    const float* __restrict__ bv,
    ushortT* __restrict__ Qbuf, ushortT* __restrict__ Kbuf,
    ushortT* __restrict__ VT,
    float* __restrict__ sparsity, float* __restrict__ vsum)
{
    __shared__ ushortT lds[4 * 128 * 64];   // As | Bq | Bk | Bv, 16KB each
    ushortT* As = lds;
    ushortT* Bq = lds + 8192;
    ushortT* Bk = lds + 16384;
    ushortT* Bv = lds + 24576;

    const int tid  = threadIdx.x;
    const int w    = tid >> 6, lane = tid & 63;
    const int quad = lane >> 4, c16 = lane & 15;
    const int wr   = w >> 1,  wc  = w & 1;
    const int m0   = blockIdx.x * 128;
    const int n0   = blockIdx.y * 128;
    const int b    = m0 >> 13;

    const int srowL = lane >> 3;                            // 0..7 within wave
    const int slc   = (((lane & 7) - (srowL & 7)) & 7) * 8; // swizzled src chunk
    const int rrot  = c16 & 7;

    f32x4 accQ[4][4], accK[4][4], accV[4][4];
#pragma unroll
    for (int i = 0; i < 4; ++i)
#pragma unroll
        for (int j = 0; j < 4; ++j) {
            accQ[i][j] = (f32x4){0.f, 0.f, 0.f, 0.f};
            accK[i][j] = (f32x4){0.f, 0.f, 0.f, 0.f};
            accV[i][j] = (f32x4){0.f, 0.f, 0.f, 0.f};
        }

    for (int k0 = 0; k0 < 512; k0 += 64) {
        __syncthreads();
#pragma unroll
        for (int c = 0; c < 4; ++c) {
            const int R = c * 32 + w * 8 + srowL;
            const int lbase = c * 2048 + w * 512;
            gload_lds16(Xf  + (size_t)(m0 + R) * 512 + k0 + slc, As + lbase);
            gload_lds16(WqT + (size_t)(n0 + R) * 512 + k0 + slc, Bq + lbase);
            gload_lds16(WkT + (size_t)(n0 + R) * 512 + k0 + slc, Bk + lbase);
            gload_lds16(WvT + (size_t)(n0 + R) * 512 + k0 + slc, Bv + lbase);
        }
        __syncthreads();
#pragma unroll
        for (int kk = 0; kk < 2; ++kk) {
            const int phk = (((kk * 4 + quad) + rrot) & 7) * 8;
            half8 af[4];
#pragma unroll
            for (int i = 0; i < 4; ++i)
                af[i] = *(const half8*)&As[(wr * 64 + i * 16 + c16) * 64 + phk];
            {
                half8 bf[4];
#pragma unroll
                for (int i = 0; i < 4; ++i)
                    bf[i] = *(const half8*)&Bq[(wc * 64 + i * 16 + c16) * 64 + phk];
#pragma unroll
                for (int i = 0; i < 4; ++i)
#pragma unroll
                    for (int j = 0; j < 4; ++j)
                        accQ[i][j] = __builtin_amdgcn_mfma_f32_16x16x32_f16(af[i], bf[j], accQ[i][j], 0, 0, 0);
            }
            {
                half8 bf[4];
#pragma unroll
                for (int i = 0; i < 4; ++i)
                    bf[i] = *(const half8*)&Bk[(wc * 64 + i * 16 + c16) * 64 + phk];
#pragma unroll
                for (int i = 0; i < 4; ++i)
#pragma unroll
                    for (int j = 0; j < 4; ++j)
                        accK[i][j] = __builtin_amdgcn_mfma_f32_16x16x32_f16(af[i], bf[j], accK[i][j], 0, 0, 0);
            }
            {
                half8 bf[4];
#pragma unroll
                for (int i = 0; i < 4; ++i)
                    bf[i] = *(const half8*)&Bv[(wc * 64 + i * 16 + c16) * 64 + phk];
#pragma unroll
                for (int i = 0; i < 4; ++i)
#pragma unroll
                    for (int j = 0; j < 4; ++j)
                        accV[i][j] = __builtin_amdgcn_mfma_f32_16x16x32_f16(af[i], bf[j], accV[i][j], 0, 0, 0);
            }
        }
    }

    // ---- Q epilogue: head-major store + sparsity ----
    {
        const int head = (n0 + wc * 64) >> 6;
        float bb[4];
#pragma unroll
        for (int j = 0; j < 4; ++j) bb[j] = bq[n0 + wc * 64 + j * 16 + c16];
        ushortT* qbase = Qbuf + ((size_t)(b * 8 + head) * 8192) * 64;
#pragma unroll
        for (int i = 0; i < 4; ++i)
#pragma unroll
            for (int r = 0; r < 4; ++r) {
                const int s = (m0 & 8191) + wr * 64 + i * 16 + quad * 4 + r;
                float p = 0.f;
#pragma unroll
                for (int j = 0; j < 4; ++j) {
                    float v = accQ[i][j][r] + bb[j];
                    qbase[(size_t)s * 64 + j * 16 + c16] = f2h(v);
                    p = fmaf(v, v, p);
                }
                p += __shfl_xor(p, 1);
                p += __shfl_xor(p, 2);
                p += __shfl_xor(p, 4);
                p += __shfl_xor(p, 8);
                if (c16 == 0)
                    sparsity[((size_t)b * H_ + head) * S_ + s] = p;
            }
    }
    // ---- K epilogue: head-major store ----
    {
        const int head = (n0 + wc * 64) >> 6;
        float bb[4];
#pragma unroll
        for (int j = 0; j < 4; ++j) bb[j] = bk[n0 + wc * 64 + j * 16 + c16];
        ushortT* kbase = Kbuf + ((size_t)(b * 8 + head) * 8192) * 64;
#pragma unroll
        for (int i = 0; i < 4; ++i)
#pragma unroll
            for (int r = 0; r < 4; ++r) {
                const int s = (m0 & 8191) + wr * 64 + i * 16 + quad * 4 + r;
#pragma unroll
                for (int j = 0; j < 4; ++j)
                    kbase[(size_t)s * 64 + j * 16 + c16] = f2h(accK[i][j][r] + bb[j]);
            }
    }
    // ---- V epilogue: LDS transpose (stride 136 pad) -> coalesced VT rows ----
    {
        __syncthreads();                       // staging LDS now reusable
        ushortT* Vt = lds;                     // [dcol 0..127][s 0..127], stride 136
#pragma unroll
        for (int j = 0; j < 4; ++j) {
            const int dcol = wc * 64 + j * 16 + c16;
            const float biasv = bv[n0 + dcol];
            float vsa = 0.f;
#pragma unroll
            for (int i = 0; i < 4; ++i)
#pragma unroll
                for (int r = 0; r < 4; ++r) {
                    const int s = wr * 64 + i * 16 + quad * 4 + r;
                    float v = accV[i][j][r] + biasv;
                    Vt[dcol * 136 + s] = f2h(v);
                    vsa += v;
                }
            vsa += __shfl_xor(vsa, 16);
            vsa += __shfl_xor(vsa, 32);
            if (quad == 0) atomicAdd(&vsum[b * 512 + n0 + dcol], vsa);
        }
        __syncthreads();
        const int dcol = tid & 127, part = tid >> 7;
        const int g = n0 + dcol, head = g >> 6, dd = g & 63;
        ushortT* vrow = VT + ((size_t)(b * 8 + head) * 64 + dd) * 8192
                        + (m0 & 8191) + part * 64;
#pragma unroll
        for (int u = 0; u < 8; ++u)
            *(ushort8*)&vrow[u * 8] = *(const ushort8*)&Vt[dcol * 136 + part * 64 + u * 8];
    }
}

// ---------------------------------------------------------------------------
// Blocks [0,32): top-45 per (b,h) via 4-level byte radix-select.
// Blocks [32,64): outbase partial: outbase[b] += bo (ks==0) + k-slice
//   of mean_flat[b] @ Wo  (b = idx>>3, ks = (idx&7)>>1, d-half = idx&1).
// ---------------------------------------------------------------------------
__global__ __launch_bounds__(256) void topk_kernel(
    const float* __restrict__ sparsity, int* __restrict__ topidx,
    const float* __restrict__ vsum, const float* __restrict__ Wo,
    const float* __restrict__ bo, float* __restrict__ outbase)
{
    __shared__ unsigned vals[S_];        // 32 KB
    __shared__ unsigned hist[8][256];    // 8 KB
    __shared__ int ssum[256];
    __shared__ unsigned prefix_s;
    __shared__ int need_s;
    __shared__ int cnt_gt_s, cnt_eq_s;
    __shared__ int eqidx[64];
    const int tid = threadIdx.x;

    if (blockIdx.x >= 32) {
        const int idx = blockIdx.x - 32;
        const int b = idx >> 3, ks = (idx & 7) >> 1, dh = idx & 1;
        const int d = dh * 256 + tid;
        float acc = (ks == 0) ? bo[d] : 0.f;
        const int r0 = ks * 128;
        for (int r = r0; r < r0 + 128; ++r) {
            float mv = vsum[b * 512 + r] * (1.0f / S_);
            acc = fmaf(mv, Wo[(size_t)r * 512 + d], acc);
        }
        atomicAdd(&outbase[b * 512 + d], acc);
        return;
    }

    const int bh = blockIdx.x;
    const unsigned* sp = (const unsigned*)(sparsity + (size_t)bh * S_);
    for (int i = tid; i < S_; i += 256) vals[i] = sp[i];

    unsigned prefix = 0;
    int need = U_;
    const int rep = tid & 7;
    for (int level = 0; level < 4; ++level) {
        const int shift = 24 - level * 8;
#pragma unroll
        for (int r = 0; r < 8; ++r) hist[r][tid] = 0;
        __syncthreads();
        const unsigned pmask = (level == 0) ? 0u : (0xFFFFFFFFu << (shift + 8));
        for (int i = tid; i < S_; i += 256) {
            unsigned v = vals[i];
            if ((v & pmask) == prefix)
                atomicAdd(&hist[rep][(v >> shift) & 255], 1u);
        }
        __syncthreads();
        int bs = 0;
#pragma unroll
        for (int r = 0; r < 8; ++r) bs += (int)hist[r][tid];
        ssum[tid] = bs;
        __syncthreads();
        for (int off = 1; off < 256; off <<= 1) {
            int add = (tid + off < 256) ? ssum[tid + off] : 0;
            __syncthreads();
            ssum[tid] += add;
            __syncthreads();
        }
        int snext = (tid == 255) ? 0 : ssum[tid + 1];
        if (ssum[tid] >= need && snext < need) {
            prefix_s = prefix | ((unsigned)tid << shift);
            need_s = need - snext;
        }
        __syncthreads();
        prefix = prefix_s;
        need = need_s;
        __syncthreads();
    }
    const unsigned T = prefix;
    if (tid == 0) { cnt_gt_s = 0; cnt_eq_s = 0; }
    __syncthreads();
    for (int i = tid; i < S_; i += 256) {
        unsigned v = vals[i];
        if (v > T) {
            int p = atomicAdd(&cnt_gt_s, 1);
            topidx[bh * U_ + p] = i;
        } else if (v == T) {
            int p = atomicAdd(&cnt_eq_s, 1);
            if (p < 64) eqidx[p] = i;
        }
    }
    __syncthreads();
    if (tid == 0) {
        int rem = U_ - cnt_gt_s;
        int n = cnt_eq_s < 64 ? cnt_eq_s : 64;
        for (int a = 0; a < rem; ++a) {     // smallest indices among ties
            int best = 1 << 30, bj = 0;
            for (int j = 0; j < n; ++j)
                if (eqidx[j] < best) { best = eqidx[j]; bj = j; }
            topidx[bh * U_ + cnt_gt_s + a] = best;
            eqidx[bj] = 1 << 30;
        }
    }
}

// ---------------------------------------------------------------------------
// MFMA attention partials (fp16), no-max softmax (|s| bounded ~4).
// Grid (NCHUNK=16, 32 bh), 256 thr.  Block = 512 keys, 4 chunks of 128.
// ---------------------------------------------------------------------------
__global__ __launch_bounds__(256, 2) void attn_mfma(
    const ushortT* __restrict__ Qbuf, const ushortT* __restrict__ Kbuf,
    const ushortT* __restrict__ VT, const int* __restrict__ topidx,
    float* __restrict__ pl, float* __restrict__ pacc)
{
    __shared__ float sc[48 * 132];          // scores f32; P fp16 in-place
    __shared__ ushortT Qb[48 * 72];         // Q fp16, scale folded, padded

    const int tid = threadIdx.x;
    const int w = tid >> 6, lane = tid & 63;
    const int quad = lane >> 4, c16 = lane & 15;
    const int bh = blockIdx.y;
    const int s_base = blockIdx.x * 512;

    for (int i = tid; i < 48 * 64; i += 256) {
        int q = i >> 6, d = i & 63;
        float v = 0.f;
        if (q < U_) {
            int s = topidx[bh * U_ + q];
            v = h2f(Qbuf[((size_t)bh * 8192 + s) * 64 + d]) * 0.125f;
        }
        Qb[q * 72 + d] = f2h(v);
    }

    f32x4 O[3];
#pragma unroll
    for (int mt = 0; mt < 3; ++mt) O[mt] = (f32x4){0.f, 0.f, 0.f, 0.f};
    float lacc[12];
#pragma unroll
    for (int qi = 0; qi < 12; ++qi) lacc[qi] = 0.f;

    __syncthreads();

    half8 qa[3][2];
#pragma unroll
    for (int mt = 0; mt < 3; ++mt)
#pragma unroll
        for (int kk = 0; kk < 2; ++kk)
            qa[mt][kk] = *(const half8*)&Qb[(mt * 16 + c16) * 72 + kk * 32 + quad * 8];

    const ushortT* kb  = Kbuf + (size_t)bh * 8192 * 64;
    const ushortT* vtb = VT + ((size_t)bh * 64 + w * 16 + c16) * 8192;

    for (int ci = 0; ci < 4; ++ci) {
        const int s0 = s_base + ci * 128;

        half8 kf[2][2];
#pragma unroll
        for (int nt2 = 0; nt2 < 2; ++nt2)
#pragma unroll
            for (int kk = 0; kk < 2; ++kk)
                kf[nt2][kk] = *(const half8*)&kb[
                    (size_t)(s0 + w * 32 + nt2 * 16 + c16) * 64 + kk * 32 + quad * 8];
        f32x4 sacc[3][2];
#pragma unroll
        for (int mt = 0; mt < 3; ++mt)
#pragma unroll
            for (int nt2 = 0; nt2 < 2; ++nt2) {
                sacc[mt][nt2] = (f32x4){0.f, 0.f, 0.f, 0.f};
#pragma unroll
                for (int kk = 0; kk < 2; ++kk)
                    sacc[mt][nt2] = __builtin_amdgcn_mfma_f32_16x16x32_f16(
                        qa[mt][kk], kf[nt2][kk], sacc[mt][nt2], 0, 0, 0);
            }
#pragma unroll
        for (int mt = 0; mt < 3; ++mt)
#pragma unroll
            for (int nt2 = 0; nt2 < 2; ++nt2)
#pragma unroll
                for (int r = 0; r < 4; ++r)
                    sc[(mt * 16 + quad * 4 + r) * 132 + w * 32 + nt2 * 16 + c16] =
                        sacc[mt][nt2][r];
        __syncthreads();

        half8 vb[4];
#pragma unroll
        for (int kk = 0; kk < 4; ++kk)
            vb[kk] = *(const half8*)&vtb[s0 + kk * 32 + quad * 8];

#pragma unroll
        for (int qi = 0; qi < 12; ++qi) {
            const int q = w * 12 + qi;
            float x0 = sc[q * 132 + lane];
            float x1 = sc[q * 132 + 64 + lane];
            ushortT u0 = f2h(__expf(x0));
            ushortT u1 = f2h(__expf(x1));
            lacc[qi] += h2f(u0) + h2f(u1);
            ushortT* pr = (ushortT*)&sc[q * 132];
            pr[lane] = u0;
            pr[lane + 64] = u1;
        }
        __syncthreads();

#pragma unroll
        for (int mt = 0; mt < 3; ++mt)
#pragma unroll
            for (int kk = 0; kk < 4; ++kk) {
                half8 pa = *(const half8*)((const ushortT*)sc +
                    (size_t)(mt * 16 + c16) * 264 + kk * 32 + quad * 8);
                O[mt] = __builtin_amdgcn_mfma_f32_16x16x32_f16(pa, vb[kk], O[mt], 0, 0, 0);
            }
        __syncthreads();
    }

#pragma unroll
    for (int mt = 0; mt < 3; ++mt)
#pragma unroll
        for (int r = 0; r < 4; ++r) {
            const int q = mt * 16 + quad * 4 + r;
            if (q < U_)
                pacc[(((size_t)bh * NCHUNK + blockIdx.x) * U_ + q) * 64 + w * 16 + c16] =
                    O[mt][r];
        }
#pragma unroll
    for (int qi = 0; qi < 12; ++qi) {
        const int q = w * 12 + qi;
        float ssum = lacc[qi];
#pragma unroll
        for (int off = 1; off < 64; off <<= 1) ssum += __shfl_xor(ssum, off);
        if (lane == 0 && q < U_)
            pl[((size_t)bh * NCHUNK + blockIdx.x) * U_ + q] = ssum;
    }
}

// ---------------------------------------------------------------------------
// Broadcast fill: out[b,s,:] = out_base[b,:]
// ---------------------------------------------------------------------------
__global__ __launch_bounds__(256) void fill_kernel(
    const float* __restrict__ outbase, float* __restrict__ out)
{
    size_t gid = (size_t)blockIdx.x * 256 + threadIdx.x;
    size_t e0 = gid * 4;
    int b = (int)(e0 >> 22);          // 8192*512 = 2^22
    int col = (int)(e0 & 511);
    float4 v = *(const float4*)&outbase[b * 512 + col];
    *(float4*)&out[e0] = v;
}

// ---------------------------------------------------------------------------
// Merged combine + correction: block (q, bh).
// ---------------------------------------------------------------------------
__global__ __launch_bounds__(512) void corr_out_kernel(
    const float* __restrict__ pl, const float* __restrict__ pacc,
    const float* __restrict__ vsum, const float* __restrict__ Wo,
    const int* __restrict__ topidx, float* __restrict__ out)
{
    __shared__ float corrS[64];
    const int q = blockIdx.x, bh = blockIdx.y;
    const int b = bh >> 3, h = bh & 7, tid = threadIdx.x;
    if (tid < 64) {
        float L = 0.f, a = 0.f;
        for (int c = 0; c < NCHUNK; ++c) {
            L += pl[((size_t)bh * NCHUNK + c) * U_ + q];
            a += pacc[(((size_t)bh * NCHUNK + c) * U_ + q) * 64 + tid];
        }
        corrS[tid] = a / L - vsum[b * 512 + h * 64 + tid] * (1.0f / S_);
    }
    __syncthreads();
    const int s = topidx[bh * U_ + q];
    const int d = tid;
    float delta = 0.f;
#pragma unroll
    for (int r = 0; r < 64; ++r)
        delta = fmaf(corrS[r], Wo[(size_t)(h * 64 + r) * 512 + d], delta);
    atomicAdd(&out[((size_t)b * S_ + s) * 512 + d], delta);
}

// ---------------------------------------------------------------------------
extern "C" void kernel_launch(void* const* d_in, const int* in_sizes, int n_in,
                              void* d_out, int out_size, void* d_ws, size_t ws_size,
                              hipStream_t stream)
{
    const float* X  = (const float*)d_in[0];
    const float* Wq = (const float*)d_in[1];
    const float* bq = (const float*)d_in[2];
    const float* Wk = (const float*)d_in[3];
    const float* bk = (const float*)d_in[4];
    const float* Wv = (const float*)d_in[5];
    const float* bv = (const float*)d_in[6];
    const float* Wo = (const float*)d_in[7];
    const float* bo = (const float*)d_in[8];
    float* out = (float*)d_out;

    char* ws = (char*)d_ws;
    size_t off = 0;
    auto alloc = [&](size_t bytes) {
        void* p = ws + off;
        off = (off + bytes + 255) & ~(size_t)255;
        return p;
    };
    ushortT* Xf   = (ushortT*)alloc((size_t)B_ * S_ * D_ * 2);
    ushortT* Qbuf = (ushortT*)alloc((size_t)B_ * S_ * D_ * 2);
    ushortT* Kbuf = (ushortT*)alloc((size_t)B_ * S_ * D_ * 2);
    ushortT* VT   = (ushortT*)alloc((size_t)B_ * S_ * D_ * 2);
    ushortT* WqT  = (ushortT*)alloc((size_t)D_ * D_ * 2);
    ushortT* WkT  = (ushortT*)alloc((size_t)D_ * D_ * 2);
    ushortT* WvT  = (ushortT*)alloc((size_t)D_ * D_ * 2);
    float* sparsity = (float*)alloc((size_t)B_ * H_ * S_ * 4);
    int*   topidx   = (int*)alloc((size_t)B_ * H_ * U_ * 4);
    float* pl       = (float*)alloc((size_t)B_ * H_ * NCHUNK * U_ * 4);
    float* pacc     = (float*)alloc((size_t)B_ * H_ * NCHUNK * U_ * 64 * 4);
    float* vsum     = (float*)alloc((size_t)B_ * 512 * 4);
    float* outbase  = (float*)alloc((size_t)B_ * 512 * 4);

    prep_kernel<<<8960, 256, 0, stream>>>(X, Xf, Wq, Wk, Wv, WqT, WkT, WvT,
                                          vsum, outbase);
    qkv_mfma<<<dim3(256, 4), 256, 0, stream>>>(Xf, WqT, WkT, WvT,
                                               bq, bk, bv, Qbuf, Kbuf, VT,
                                               sparsity, vsum);
    topk_kernel<<<64, 256, 0, stream>>>(sparsity, topidx, vsum, Wo, bo, outbase);
    attn_mfma<<<dim3(NCHUNK, B_ * H_), 256, 0, stream>>>(Qbuf, Kbuf, VT, topidx,
                                                         pl, pacc);
    fill_kernel<<<(B_ * S_ * D_ / 4 + 255) / 256, 256, 0, stream>>>(outbase, out);
    corr_out_kernel<<<dim3(U_, B_ * H_), 512, 0, stream>>>(pl, pacc, vsum, Wo,
                                                           topidx, out);
}

// Round 10
// 280.751 us; speedup vs baseline: 1.0430x; 1.0430x over previous
//
#include <hip/hip_runtime.h>
#include <hip/hip_fp16.h>
#include <math.h>

#define B_ 4
#define S_ 8192
#define D_ 512
#define H_ 8
#define U_ 45            // int(5*ln(8193)) = 45
#define NCHUNK 16        // 512 keys per attention block

typedef unsigned short ushortT;
typedef __attribute__((ext_vector_type(8))) _Float16 half8;
typedef __attribute__((ext_vector_type(4))) float f32x4;

__device__ __forceinline__ ushortT f2h(float f) {
    return __half_as_ushort(__float2half(f));    // RNE
}
__device__ __forceinline__ float h2f(ushortT u) {
    return __half2float(__ushort_as_half(u));
}

__device__ __forceinline__ void gload_lds16(const ushortT* g, ushortT* l) {
    __builtin_amdgcn_global_load_lds(
        (const __attribute__((address_space(1))) void*)g,
        (__attribute__((address_space(3))) void*)l,
        16, 0, 0);
}

// ---------------------------------------------------------------------------
// Fused pre-pass: blocks [0,8192): X fp32 -> fp16 (block 0 zeroes vsum +
// outbase).  Blocks [8192, 8960): weight transpose+convert WT[n][k]=W[k][n].
// ---------------------------------------------------------------------------
__global__ __launch_bounds__(256) void prep_kernel(
    const float* __restrict__ X, ushortT* __restrict__ Xf,
    const float* __restrict__ Wq, const float* __restrict__ Wk,
    const float* __restrict__ Wv,
    ushortT* __restrict__ WqT, ushortT* __restrict__ WkT,
    ushortT* __restrict__ WvT,
    float* __restrict__ vsum, float* __restrict__ outbase)
{
    __shared__ float t[32][33];
    const int bx = blockIdx.x;
    if (bx < 8192) {
        if (bx == 0) {
            float4 z = {0.f, 0.f, 0.f, 0.f};
            *(float4*)&vsum[threadIdx.x * 8]        = z;
            *(float4*)&vsum[threadIdx.x * 8 + 4]    = z;
            *(float4*)&outbase[threadIdx.x * 8]     = z;
            *(float4*)&outbase[threadIdx.x * 8 + 4] = z;
        }
        size_t i = ((size_t)bx * 256 + threadIdx.x) * 8;
        float4 a = *(const float4*)(X + i);
        float4 b = *(const float4*)(X + i + 4);
        *(ushort4*)(Xf + i)     = make_ushort4(f2h(a.x), f2h(a.y), f2h(a.z), f2h(a.w));
        *(ushort4*)(Xf + i + 4) = make_ushort4(f2h(b.x), f2h(b.y), f2h(b.z), f2h(b.w));
    } else {
        const int idx = bx - 8192;
        const int z = idx >> 8, rem = idx & 255;
        const int r0 = (rem >> 4) * 32, c0 = (rem & 15) * 32;
        const float* W = (z == 0) ? Wq : (z == 1) ? Wk : Wv;
        ushortT* O = (z == 0) ? WqT : (z == 1) ? WkT : WvT;
        const int tx = threadIdx.x & 31, ty4 = (threadIdx.x >> 5) * 4;
#pragma unroll
        for (int i = 0; i < 4; ++i)
            t[ty4 + i][tx] = W[(size_t)(r0 + ty4 + i) * 512 + c0 + tx];
        __syncthreads();
#pragma unroll
        for (int i = 0; i < 4; ++i)
            O[(size_t)(c0 + ty4 + i) * 512 + r0 + tx] = f2h(t[tx][ty4 + i]);
    }
}

// ---------------------------------------------------------------------------
// MFMA QKV projection, fp16, BK=64, 3-pass (R8 config, measured 82.5us —
// the R9 fused-3-streams version spilled: 192 VGPR of accumulators vs 128
// budget; WRITE_SIZE +57MB scratch; reverted).
// grid (256, 12): y 0-3 Q n-tiles, 4-7 K n-tiles, 8-11 V column-tiles.
// 128x128 tile, 4 waves 2x2, wave = 64x64.  launch_bounds (256,2) measured
// best (R6's (256,4) regressed).  8-chunk rotate swizzle: 0 conflicts.
// ---------------------------------------------------------------------------
__global__ __launch_bounds__(256, 2) void qkv_mfma(
    const ushortT* __restrict__ Xf,
    const ushortT* __restrict__ WqT, const ushortT* __restrict__ WkT,
    const ushortT* __restrict__ WvT,
    const float* __restrict__ bq, const float* __restrict__ bk,
    const float* __restrict__ bv,
    ushortT* __restrict__ Qbuf, ushortT* __restrict__ Kbuf,
    ushortT* __restrict__ VT,
    float* __restrict__ sparsity, float* __restrict__ vsum)
{
    __shared__ ushortT lds[2 * 128 * 64];   // A | B, 16KB each
    ushortT* As = lds;
    ushortT* Bs = lds + 8192;

    const int tid  = threadIdx.x;
    const int w    = tid >> 6, lane = tid & 63;
    const int quad = lane >> 4, c16 = lane & 15;
    const int wr   = w >> 1,  wc  = w & 1;
    const int mat  = blockIdx.y >> 2;        // 0=Q 1=K 2=V
    const int nt   = blockIdx.y & 3;
    const int m0   = blockIdx.x * 128;
    const int n0   = nt * 128;

    const int srowL = lane >> 3;                            // 0..7 within wave
    const int slc   = (((lane & 7) - (srowL & 7)) & 7) * 8; // swizzled src chunk
    const int rrot  = c16 & 7;

    const ushortT* Ag = (mat == 2) ? WvT : Xf;
    const ushortT* Bg = (mat == 0) ? WqT : (mat == 1) ? WkT : Xf;
    const int arow0 = (mat == 2) ? n0 : m0;
    const int brow0 = (mat == 2) ? m0 : n0;

    f32x4 acc[4][4];
#pragma unroll
    for (int i = 0; i < 4; ++i)
#pragma unroll
        for (int j = 0; j < 4; ++j) acc[i][j] = (f32x4){0.f, 0.f, 0.f, 0.f};

    for (int k0 = 0; k0 < 512; k0 += 64) {
        __syncthreads();
#pragma unroll
        for (int c = 0; c < 4; ++c) {
            const int R = c * 32 + w * 8 + srowL;
            const int lbase = c * 2048 + w * 512;          // halves
            gload_lds16(Ag + (size_t)(arow0 + R) * 512 + k0 + slc, As + lbase);
            gload_lds16(Bg + (size_t)(brow0 + R) * 512 + k0 + slc, Bs + lbase);
        }
        __syncthreads();
#pragma unroll
        for (int kk = 0; kk < 2; ++kk) {
            const int phk = (((kk * 4 + quad) + rrot) & 7) * 8;
            half8 af[4], bf[4];
#pragma unroll
            for (int i = 0; i < 4; ++i) {
                af[i] = *(const half8*)&As[(wr * 64 + i * 16 + c16) * 64 + phk];
                bf[i] = *(const half8*)&Bs[(wc * 64 + i * 16 + c16) * 64 + phk];
            }
#pragma unroll
            for (int i = 0; i < 4; ++i)
#pragma unroll
                for (int j = 0; j < 4; ++j)
                    acc[i][j] = __builtin_amdgcn_mfma_f32_16x16x32_f16(af[i], bf[j], acc[i][j], 0, 0, 0);
        }
    }

    // ---- epilogue ----
    if (mat == 0) {
        // Q: store head-major fp16 + sparsity (sum of squares per row)
        const int b = m0 >> 13;
        const int head = (n0 + wc * 64) >> 6;
        float bb[4];
#pragma unroll
        for (int j = 0; j < 4; ++j) bb[j] = bq[n0 + wc * 64 + j * 16 + c16];
        ushortT* qbase = Qbuf + ((size_t)(b * 8 + head) * 8192) * 64;
#pragma unroll
        for (int i = 0; i < 4; ++i)
#pragma unroll
            for (int r = 0; r < 4; ++r) {
                const int s = (m0 & 8191) + wr * 64 + i * 16 + quad * 4 + r;
                float p = 0.f;
#pragma unroll
                for (int j = 0; j < 4; ++j) {
                    float v = acc[i][j][r] + bb[j];
                    qbase[(size_t)s * 64 + j * 16 + c16] = f2h(v);
                    p = fmaf(v, v, p);
                }
                p += __shfl_xor(p, 1);
                p += __shfl_xor(p, 2);
                p += __shfl_xor(p, 4);
                p += __shfl_xor(p, 8);
                if (c16 == 0)
                    sparsity[((size_t)b * H_ + head) * S_ + s] = p;
            }
    } else if (mat == 1) {
        const int b = m0 >> 13;
        const int head = (n0 + wc * 64) >> 6;
        float bb[4];
#pragma unroll
        for (int j = 0; j < 4; ++j) bb[j] = bk[n0 + wc * 64 + j * 16 + c16];
        ushortT* kbase = Kbuf + ((size_t)(b * 8 + head) * 8192) * 64;
#pragma unroll
        for (int i = 0; i < 4; ++i)
#pragma unroll
            for (int r = 0; r < 4; ++r) {
                const int s = (m0 & 8191) + wr * 64 + i * 16 + quad * 4 + r;
#pragma unroll
                for (int j = 0; j < 4; ++j)
                    kbase[(size_t)s * 64 + j * 16 + c16] = f2h(acc[i][j][r] + bb[j]);
            }
    } else {
        // V transposed: VT[((b*8+head)*64 + dd)*8192 + s]
        const int b = m0 >> 13;
        const int sbase = (m0 & 8191) + wc * 64;
#pragma unroll
        for (int i = 0; i < 4; ++i)
#pragma unroll
            for (int r = 0; r < 4; ++r) {
                const int dcol = n0 + wr * 64 + i * 16 + quad * 4 + r;
                const int head = dcol >> 6, dd = dcol & 63;
                const float biasv = bv[dcol];
                ushortT* vrow = VT + ((size_t)(b * 8 + head) * 64 + dd) * 8192;
                float vsa = 0.f;
#pragma unroll
                for (int j = 0; j < 4; ++j) {
                    float v = acc[i][j][r] + biasv;
                    vrow[sbase + j * 16 + c16] = f2h(v);
                    vsa += v;
                }
                vsa += __shfl_xor(vsa, 1);
                vsa += __shfl_xor(vsa, 2);
                vsa += __shfl_xor(vsa, 4);
                vsa += __shfl_xor(vsa, 8);
                if (c16 == 0) atomicAdd(&vsum[b * 512 + dcol], vsa);
            }
    }
}

// ---------------------------------------------------------------------------
// Blocks [0,32): top-45 per (b,h) via 4-level byte radix-select.
// Blocks [32,64): outbase partial: outbase[b] += bo (ks==0) + k-slice
//   of mean_flat[b] @ Wo  (b = idx>>3, ks = (idx&7)>>1, d-half = idx&1).
// ---------------------------------------------------------------------------
__global__ __launch_bounds__(256) void topk_kernel(
    const float* __restrict__ sparsity, int* __restrict__ topidx,
    const float* __restrict__ vsum, const float* __restrict__ Wo,
    const float* __restrict__ bo, float* __restrict__ outbase)
{
    __shared__ unsigned vals[S_];        // 32 KB
    __shared__ unsigned hist[8][256];    // 8 KB
    __shared__ int ssum[256];
    __shared__ unsigned prefix_s;
    __shared__ int need_s;
    __shared__ int cnt_gt_s, cnt_eq_s;
    __shared__ int eqidx[64];
    const int tid = threadIdx.x;

    if (blockIdx.x >= 32) {
        const int idx = blockIdx.x - 32;
        const int b = idx >> 3, ks = (idx & 7) >> 1, dh = idx & 1;
        const int d = dh * 256 + tid;
        float acc = (ks == 0) ? bo[d] : 0.f;
        const int r0 = ks * 128;
        for (int r = r0; r < r0 + 128; ++r) {
            float mv = vsum[b * 512 + r] * (1.0f / S_);
            acc = fmaf(mv, Wo[(size_t)r * 512 + d], acc);
        }
        atomicAdd(&outbase[b * 512 + d], acc);
        return;
    }

    const int bh = blockIdx.x;
    const unsigned* sp = (const unsigned*)(sparsity + (size_t)bh * S_);
    for (int i = tid; i < S_; i += 256) vals[i] = sp[i];

    unsigned prefix = 0;
    int need = U_;
    const int rep = tid & 7;
    for (int level = 0; level < 4; ++level) {
        const int shift = 24 - level * 8;
#pragma unroll
        for (int r = 0; r < 8; ++r) hist[r][tid] = 0;
        __syncthreads();
        const unsigned pmask = (level == 0) ? 0u : (0xFFFFFFFFu << (shift + 8));
        for (int i = tid; i < S_; i += 256) {
            unsigned v = vals[i];
            if ((v & pmask) == prefix)
                atomicAdd(&hist[rep][(v >> shift) & 255], 1u);
        }
        __syncthreads();
        int bs = 0;
#pragma unroll
        for (int r = 0; r < 8; ++r) bs += (int)hist[r][tid];
        ssum[tid] = bs;
        __syncthreads();
        for (int off = 1; off < 256; off <<= 1) {
            int add = (tid + off < 256) ? ssum[tid + off] : 0;
            __syncthreads();
            ssum[tid] += add;
            __syncthreads();
        }
        int snext = (tid == 255) ? 0 : ssum[tid + 1];
        if (ssum[tid] >= need && snext < need) {
            prefix_s = prefix | ((unsigned)tid << shift);
            need_s = need - snext;
        }
        __syncthreads();
        prefix = prefix_s;
        need = need_s;
        __syncthreads();
    }
    const unsigned T = prefix;
    if (tid == 0) { cnt_gt_s = 0; cnt_eq_s = 0; }
    __syncthreads();
    for (int i = tid; i < S_; i += 256) {
        unsigned v = vals[i];
        if (v > T) {
            int p = atomicAdd(&cnt_gt_s, 1);
            topidx[bh * U_ + p] = i;
        } else if (v == T) {
            int p = atomicAdd(&cnt_eq_s, 1);
            if (p < 64) eqidx[p] = i;
        }
    }
    __syncthreads();
    if (tid == 0) {
        int rem = U_ - cnt_gt_s;
        int n = cnt_eq_s < 64 ? cnt_eq_s : 64;
        for (int a = 0; a < rem; ++a) {     // smallest indices among ties
            int best = 1 << 30, bj = 0;
            for (int j = 0; j < n; ++j)
                if (eqidx[j] < best) { best = eqidx[j]; bj = j; }
            topidx[bh * U_ + cnt_gt_s + a] = best;
            eqidx[bj] = 1 << 30;
        }
    }
}

// ---------------------------------------------------------------------------
// MFMA attention partials (fp16), no-max softmax (|s| bounded ~4).
// Grid (NCHUNK=16, 32 bh), 256 thr.  Block = 512 keys, 4 chunks of 128.
// ---------------------------------------------------------------------------
__global__ __launch_bounds__(256, 2) void attn_mfma(
    const ushortT* __restrict__ Qbuf, const ushortT* __restrict__ Kbuf,
    const ushortT* __restrict__ VT, const int* __restrict__ topidx,
    float* __restrict__ pl, float* __restrict__ pacc)
{
    __shared__ float sc[48 * 132];          // scores f32; P fp16 in-place
    __shared__ ushortT Qb[48 * 72];         // Q fp16, scale folded, padded

    const int tid = threadIdx.x;
    const int w = tid >> 6, lane = tid & 63;
    const int quad = lane >> 4, c16 = lane & 15;
    const int bh = blockIdx.y;
    const int s_base = blockIdx.x * 512;

    for (int i = tid; i < 48 * 64; i += 256) {
        int q = i >> 6, d = i & 63;
        float v = 0.f;
        if (q < U_) {
            int s = topidx[bh * U_ + q];
            v = h2f(Qbuf[((size_t)bh * 8192 + s) * 64 + d]) * 0.125f;
        }
        Qb[q * 72 + d] = f2h(v);
    }

    f32x4 O[3];
#pragma unroll
    for (int mt = 0; mt < 3; ++mt) O[mt] = (f32x4){0.f, 0.f, 0.f, 0.f};
    float lacc[12];
#pragma unroll
    for (int qi = 0; qi < 12; ++qi) lacc[qi] = 0.f;

    __syncthreads();

    half8 qa[3][2];
#pragma unroll
    for (int mt = 0; mt < 3; ++mt)
#pragma unroll
        for (int kk = 0; kk < 2; ++kk)
            qa[mt][kk] = *(const half8*)&Qb[(mt * 16 + c16) * 72 + kk * 32 + quad * 8];

    const ushortT* kb  = Kbuf + (size_t)bh * 8192 * 64;
    const ushortT* vtb = VT + ((size_t)bh * 64 + w * 16 + c16) * 8192;

    for (int ci = 0; ci < 4; ++ci) {
        const int s0 = s_base + ci * 128;

        half8 kf[2][2];
#pragma unroll
        for (int nt2 = 0; nt2 < 2; ++nt2)
#pragma unroll
            for (int kk = 0; kk < 2; ++kk)
                kf[nt2][kk] = *(const half8*)&kb[
                    (size_t)(s0 + w * 32 + nt2 * 16 + c16) * 64 + kk * 32 + quad * 8];
        f32x4 sacc[3][2];
#pragma unroll
        for (int mt = 0; mt < 3; ++mt)
#pragma unroll
            for (int nt2 = 0; nt2 < 2; ++nt2) {
                sacc[mt][nt2] = (f32x4){0.f, 0.f, 0.f, 0.f};
#pragma unroll
                for (int kk = 0; kk < 2; ++kk)
                    sacc[mt][nt2] = __builtin_amdgcn_mfma_f32_16x16x32_f16(
                        qa[mt][kk], kf[nt2][kk], sacc[mt][nt2], 0, 0, 0);
            }
#pragma unroll
        for (int mt = 0; mt < 3; ++mt)
#pragma unroll
            for (int nt2 = 0; nt2 < 2; ++nt2)
#pragma unroll
                for (int r = 0; r < 4; ++r)
                    sc[(mt * 16 + quad * 4 + r) * 132 + w * 32 + nt2 * 16 + c16] =
                        sacc[mt][nt2][r];
        __syncthreads();

        half8 vb[4];
#pragma unroll
        for (int kk = 0; kk < 4; ++kk)
            vb[kk] = *(const half8*)&vtb[s0 + kk * 32 + quad * 8];

#pragma unroll
        for (int qi = 0; qi < 12; ++qi) {
            const int q = w * 12 + qi;
            float x0 = sc[q * 132 + lane];
            float x1 = sc[q * 132 + 64 + lane];
            ushortT u0 = f2h(__expf(x0));
            ushortT u1 = f2h(__expf(x1));
            lacc[qi] += h2f(u0) + h2f(u1);
            ushortT* pr = (ushortT*)&sc[q * 132];
            pr[lane] = u0;
            pr[lane + 64] = u1;
        }
        __syncthreads();

#pragma unroll
        for (int mt = 0; mt < 3; ++mt)
#pragma unroll
            for (int kk = 0; kk < 4; ++kk) {
                half8 pa = *(const half8*)((const ushortT*)sc +
                    (size_t)(mt * 16 + c16) * 264 + kk * 32 + quad * 8);
                O[mt] = __builtin_amdgcn_mfma_f32_16x16x32_f16(pa, vb[kk], O[mt], 0, 0, 0);
            }
        __syncthreads();
    }

#pragma unroll
    for (int mt = 0; mt < 3; ++mt)
#pragma unroll
        for (int r = 0; r < 4; ++r) {
            const int q = mt * 16 + quad * 4 + r;
            if (q < U_)
                pacc[(((size_t)bh * NCHUNK + blockIdx.x) * U_ + q) * 64 + w * 16 + c16] =
                    O[mt][r];
        }
#pragma unroll
    for (int qi = 0; qi < 12; ++qi) {
        const int q = w * 12 + qi;
        float ssum = lacc[qi];
#pragma unroll
        for (int off = 1; off < 64; off <<= 1) ssum += __shfl_xor(ssum, off);
        if (lane == 0 && q < U_)
            pl[((size_t)bh * NCHUNK + blockIdx.x) * U_ + q] = ssum;
    }
}

// ---------------------------------------------------------------------------
// Broadcast fill: out[b,s,:] = out_base[b,:]
// ---------------------------------------------------------------------------
__global__ __launch_bounds__(256) void fill_kernel(
    const float* __restrict__ outbase, float* __restrict__ out)
{
    size_t gid = (size_t)blockIdx.x * 256 + threadIdx.x;
    size_t e0 = gid * 4;
    int b = (int)(e0 >> 22);          // 8192*512 = 2^22
    int col = (int)(e0 & 511);
    float4 v = *(const float4*)&outbase[b * 512 + col];
    *(float4*)&out[e0] = v;
}

// ---------------------------------------------------------------------------
// Merged combine + correction: block (q, bh).
// ---------------------------------------------------------------------------
__global__ __launch_bounds__(512) void corr_out_kernel(
    const float* __restrict__ pl, const float* __restrict__ pacc,
    const float* __restrict__ vsum, const float* __restrict__ Wo,
    const int* __restrict__ topidx, float* __restrict__ out)
{
    __shared__ float corrS[64];
    const int q = blockIdx.x, bh = blockIdx.y;
    const int b = bh >> 3, h = bh & 7, tid = threadIdx.x;
    if (tid < 64) {
        float L = 0.f, a = 0.f;
        for (int c = 0; c < NCHUNK; ++c) {
            L += pl[((size_t)bh * NCHUNK + c) * U_ + q];
            a += pacc[(((size_t)bh * NCHUNK + c) * U_ + q) * 64 + tid];
        }
        corrS[tid] = a / L - vsum[b * 512 + h * 64 + tid] * (1.0f / S_);
    }
    __syncthreads();
    const int s = topidx[bh * U_ + q];
    const int d = tid;
    float delta = 0.f;
#pragma unroll
    for (int r = 0; r < 64; ++r)
        delta = fmaf(corrS[r], Wo[(size_t)(h * 64 + r) * 512 + d], delta);
    atomicAdd(&out[((size_t)b * S_ + s) * 512 + d], delta);
}

// ---------------------------------------------------------------------------
extern "C" void kernel_launch(void* const* d_in, const int* in_sizes, int n_in,
                              void* d_out, int out_size, void* d_ws, size_t ws_size,
                              hipStream_t stream)
{
    const float* X  = (const float*)d_in[0];
    const float* Wq = (const float*)d_in[1];
    const float* bq = (const float*)d_in[2];
    const float* Wk = (const float*)d_in[3];
    const float* bk = (const float*)d_in[4];
    const float* Wv = (const float*)d_in[5];
    const float* bv = (const float*)d_in[6];
    const float* Wo = (const float*)d_in[7];
    const float* bo = (const float*)d_in[8];
    float* out = (float*)d_out;

    char* ws = (char*)d_ws;
    size_t off = 0;
    auto alloc = [&](size_t bytes) {
        void* p = ws + off;
        off = (off + bytes + 255) & ~(size_t)255;
        return p;
    };
    ushortT* Xf   = (ushortT*)alloc((size_t)B_ * S_ * D_ * 2);
    ushortT* Qbuf = (ushortT*)alloc((size_t)B_ * S_ * D_ * 2);
    ushortT* Kbuf = (ushortT*)alloc((size_t)B_ * S_ * D_ * 2);
    ushortT* VT   = (ushortT*)alloc((size_t)B_ * S_ * D_ * 2);
    ushortT* WqT  = (ushortT*)alloc((size_t)D_ * D_ * 2);
    ushortT* WkT  = (ushortT*)alloc((size_t)D_ * D_ * 2);
    ushortT* WvT  = (ushortT*)alloc((size_t)D_ * D_ * 2);
    float* sparsity = (float*)alloc((size_t)B_ * H_ * S_ * 4);
    int*   topidx   = (int*)alloc((size_t)B_ * H_ * U_ * 4);
    float* pl       = (float*)alloc((size_t)B_ * H_ * NCHUNK * U_ * 4);
    float* pacc     = (float*)alloc((size_t)B_ * H_ * NCHUNK * U_ * 64 * 4);
    float* vsum     = (float*)alloc((size_t)B_ * 512 * 4);
    float* outbase  = (float*)alloc((size_t)B_ * 512 * 4);

    prep_kernel<<<8960, 256, 0, stream>>>(X, Xf, Wq, Wk, Wv, WqT, WkT, WvT,
                                          vsum, outbase);
    qkv_mfma<<<dim3(256, 12), 256, 0, stream>>>(Xf, WqT, WkT, WvT,
                                                bq, bk, bv, Qbuf, Kbuf, VT,
                                                sparsity, vsum);
    topk_kernel<<<64, 256, 0, stream>>>(sparsity, topidx, vsum, Wo, bo, outbase);
    attn_mfma<<<dim3(NCHUNK, B_ * H_), 256, 0, stream>>>(Qbuf, Kbuf, VT, topidx,
                                                         pl, pacc);
    fill_kernel<<<(B_ * S_ * D_ / 4 + 255) / 256, 256, 0, stream>>>(outbase, out);
    corr_out_kernel<<<dim3(U_, B_ * H_), 512, 0, stream>>>(pl, pacc, vsum, Wo,
                                                           topidx, out);
}